// Round 1
// baseline (5100.064 us; speedup 1.0000x reference)
//
#include <hip/hip_runtime.h>
#include <stdint.h>

#define HOR 128
#define NPATH 4096
#define BATCH 8
#define DM 512
#define H 64
#define BN (BATCH*NPATH)

// ---------------- threefry2x32 (JAX-exact) ----------------
__device__ __forceinline__ uint32_t rotl32(uint32_t x, int r) {
  return (x << r) | (x >> (32 - r));
}

__device__ __forceinline__ void tf2x32(uint32_t k0, uint32_t k1,
                                       uint32_t& x0, uint32_t& x1) {
  uint32_t k2 = k0 ^ k1 ^ 0x1BD11BDAu;
  x0 += k0; x1 += k1;
#define TFR4(a,b,c,d) \
  x0 += x1; x1 = rotl32(x1,a); x1 ^= x0; \
  x0 += x1; x1 = rotl32(x1,b); x1 ^= x0; \
  x0 += x1; x1 = rotl32(x1,c); x1 ^= x0; \
  x0 += x1; x1 = rotl32(x1,d); x1 ^= x0;
  TFR4(13,15,26,6)  x0 += k1; x1 += k2 + 1u;
  TFR4(17,29,16,24) x0 += k2; x1 += k0 + 2u;
  TFR4(13,15,26,6)  x0 += k0; x1 += k1 + 3u;
  TFR4(17,29,16,24) x0 += k1; x1 += k2 + 4u;
  TFR4(13,15,26,6)  x0 += k2; x1 += k0 + 5u;
#undef TFR4
}

// ---------------- math helpers ----------------
__device__ __forceinline__ float rcpf(float x) { return __builtin_amdgcn_rcpf(x); }
__device__ __forceinline__ float siluf(float x) {
  return x * rcpf(1.0f + __expf(-x));
}
__device__ __forceinline__ float softplusf(float x) {
  return fmaxf(x, 0.0f) + log1pf(__expf(-fabsf(x)));
}

// bits -> u(-1,1) -> sqrt(2)*erfinv(u)   (matches jax.random.normal f32 path)
__device__ __forceinline__ float bits_to_normal(uint32_t bits) {
  uint32_t fb = (bits >> 9) | 0x3F800000u;
  float f = __uint_as_float(fb) - 1.0f;          // [0,1)
  float u = fmaf(f, 2.0f, -0.99999994f);         // lo = nextafter(-1,0); (hi-lo) rounds to 2.0f
  u = fmaxf(u, -0.99999994f);
  float w = -log1pf(-u * u);
  float p;
  if (w < 5.0f) {
    w = w - 2.5f;
    p = 2.81022636e-08f;
    p = fmaf(p, w, 3.43273939e-07f);
    p = fmaf(p, w, -3.5233877e-06f);
    p = fmaf(p, w, -4.39150654e-06f);
    p = fmaf(p, w, 0.00021858087f);
    p = fmaf(p, w, -0.00125372503f);
    p = fmaf(p, w, -0.00417768164f);
    p = fmaf(p, w, 0.246640727f);
    p = fmaf(p, w, 1.50140941f);
  } else {
    w = sqrtf(w) - 3.0f;
    p = -0.000200214257f;
    p = fmaf(p, w, 0.000100950558f);
    p = fmaf(p, w, 0.00134934322f);
    p = fmaf(p, w, -0.00367342844f);
    p = fmaf(p, w, 0.00573950773f);
    p = fmaf(p, w, -0.0076224613f);
    p = fmaf(p, w, 0.00943887047f);
    p = fmaf(p, w, 1.00167406f);
    p = fmaf(p, w, 2.83297682f);
  }
  return 1.41421356237f * (p * u);
}

// ws layout (floats): [0,512) base_f1[b][j], [512,1024) base_g1[b][j],
// (u32 view) [1024,1152) keyA[t], [1152,1280) keyB[t]

// blocks 0..7: per-batch precompute (base vecs, mu, sigma). block 8: step keys.
__global__ void k_pre(const float* __restrict__ h_t,
                      const float* __restrict__ W_f1, const float* __restrict__ b_f1,
                      const float* __restrict__ W_g1, const float* __restrict__ b_g1,
                      const float* __restrict__ W_mu, const float* __restrict__ b_mu,
                      const float* __restrict__ W_sig, const float* __restrict__ b_sig,
                      float* __restrict__ out, float* __restrict__ ws) {
  int j = threadIdx.x;           // 0..63
  int b = blockIdx.x;
  if (b == 8) {
    // partitionable split: key_t = threefry((0,42), (0, t))
    uint32_t* keyA = (uint32_t*)ws + 1024;
    uint32_t* keyB = (uint32_t*)ws + 1152;
    for (int t = j; t < HOR; t += 64) {
      uint32_t x0 = 0u, x1 = (uint32_t)t;
      tf2x32(0u, 42u, x0, x1);
      keyA[t] = x0; keyB[t] = x1;
    }
    return;
  }
  const float* h = h_t + b * DM;
  float accF = b_f1[j], accG = b_g1[j];
  float pm = 0.0f, ps = 0.0f;
  #pragma unroll 4
  for (int d = 0; d < DM; ++d) {
    float hv = h[d];
    accF = fmaf(hv, W_f1[d * H + j], accF);
    accG = fmaf(hv, W_g1[d * H + j], accG);
  }
  ws[b * H + j] = accF;
  ws[512 + b * H + j] = accG;
  for (int d = j; d < DM; d += 64) {
    pm = fmaf(h[d], W_mu[d], pm);
    ps = fmaf(h[d], W_sig[d], ps);
  }
  #pragma unroll
  for (int off = 32; off > 0; off >>= 1) {
    pm += __shfl_down(pm, off);
    ps += __shfl_down(ps, off);
  }
  if (j == 0) {
    out[BN * HOR + b] = pm + b_mu[0];                       // mu
    out[BN * HOR + 8 + b] = softplusf(ps + b_sig[0]) + 1e-6f; // sigma
  }
}

__global__ __launch_bounds__(64, 2)
void k_sde(const float* __restrict__ ip,
           const float* __restrict__ W_f1, const float* __restrict__ W_f2,
           const float* __restrict__ b_f2, const float* __restrict__ W_f3,
           const float* __restrict__ b_f3, const float* __restrict__ W_g1,
           const float* __restrict__ W_g2, const float* __restrict__ b_g2,
           float* __restrict__ out, const float* __restrict__ ws) {
  __shared__ __align__(16) float sW[H * H];   // sW[j*64+k] = W_f2[k][j]
  __shared__ float sF1y[H], sF1t[H], sG1y[H], sG1t[H], sF3[H], sG2[H], sBf2[H], sBF[H], sBG[H];
  __shared__ uint32_t sKA[HOR], sKB[HOR];

  int tid = threadIdx.x;                       // 0..63
  int r = blockIdx.x * 64 + tid;               // path-row, block-uniform batch
  int b = r >> 12;                             // n_paths = 4096

  // transpose W_f2 into LDS (thread = k; LDS writes conflict-free)
  #pragma unroll 1
  for (int j = 0; j < H; ++j) sW[j * H + tid] = W_f2[tid * H + j];
  sF1y[tid] = W_f1[512 * H + tid];
  sF1t[tid] = W_f1[513 * H + tid];
  sG1y[tid] = W_g1[512 * H + tid];
  sG1t[tid] = W_g1[513 * H + tid];
  sF3[tid]  = W_f3[tid];
  sG2[tid]  = W_g2[tid];
  sBf2[tid] = b_f2[tid];
  sBF[tid]  = ws[b * H + tid];
  sBG[tid]  = ws[512 + b * H + tid];
  const uint32_t* kws = (const uint32_t*)ws;
  sKA[tid]      = kws[1024 + tid];
  sKA[tid + 64] = kws[1024 + tid + 64];
  sKB[tid]      = kws[1152 + tid];
  sKB[tid + 64] = kws[1152 + tid + 64];
  __syncthreads();

  const float bf3 = b_f3[0];
  const float bg2 = b_g2[0];
  float y = logf(ip[b]);
  float* outp = out + (size_t)r * HOR;
  const uint32_t cnt = (uint32_t)r;

  #pragma unroll 1
  for (int t = 0; t < HOR; ++t) {
    float tt = (float)t;

    // noise: partitionable random_bits -> o1 ^ o2
    uint32_t x0 = 0u, x1 = cnt;
    tf2x32(sKA[t], sKB[t], x0, x1);
    float z = bits_to_normal(x0 ^ x1);

    // h1 = silu(base_f1 + y*Wf1[512] + t*Wf1[513])
    float h1[H];
    #pragma unroll
    for (int k = 0; k < H; ++k) {
      float pre = fmaf(y, sF1y[k], fmaf(tt, sF1t[k], sBF[k]));
      h1[k] = siluf(pre);
    }

    // f = b_f3 + sum_j silu(b_f2[j] + h1 . Wf2[:,j]) * Wf3[j]
    float facc = bf3;
    #pragma unroll 1
    for (int j = 0; j < H; ++j) {
      float a = sBf2[j];
      const float4* wr = (const float4*)(sW + j * H);
      #pragma unroll
      for (int k4 = 0; k4 < H / 4; ++k4) {
        float4 w = wr[k4];   // wave-uniform address -> LDS broadcast
        a = fmaf(h1[4 * k4 + 0], w.x, a);
        a = fmaf(h1[4 * k4 + 1], w.y, a);
        a = fmaf(h1[4 * k4 + 2], w.z, a);
        a = fmaf(h1[4 * k4 + 3], w.w, a);
      }
      facc = fmaf(siluf(a), sF3[j], facc);
    }

    // g = softplus(b_g2 + sum_k silu(base_g1 + y*Wg1[512] + t*Wg1[513]) * Wg2) + 1e-6
    float gacc = bg2;
    #pragma unroll
    for (int k = 0; k < H; ++k) {
      float pre = fmaf(y, sG1y[k], fmaf(tt, sG1t[k], sBG[k]));
      gacc = fmaf(siluf(pre), sG2[k], gacc);
    }
    float g = softplusf(gacc) + 1e-6f;

    y = (y + facc) + g * z;     // dt = 1, sqrt_dt = 1
    float yl = fminf(fmaxf(y, -20.0f), 20.0f);
    outp[t] = __expf(yl);
  }
}

extern "C" void kernel_launch(void* const* d_in, const int* in_sizes, int n_in,
                              void* d_out, int out_size, void* d_ws, size_t ws_size,
                              hipStream_t stream) {
  const float* h_t   = (const float*)d_in[0];
  const float* ip    = (const float*)d_in[1];
  const float* W_f1  = (const float*)d_in[2];
  const float* b_f1  = (const float*)d_in[3];
  const float* W_f2  = (const float*)d_in[4];
  const float* b_f2  = (const float*)d_in[5];
  const float* W_f3  = (const float*)d_in[6];
  const float* b_f3  = (const float*)d_in[7];
  const float* W_g1  = (const float*)d_in[8];
  const float* b_g1  = (const float*)d_in[9];
  const float* W_g2  = (const float*)d_in[10];
  const float* b_g2  = (const float*)d_in[11];
  const float* W_mu  = (const float*)d_in[12];
  const float* b_mu  = (const float*)d_in[13];
  const float* W_sig = (const float*)d_in[14];
  const float* b_sig = (const float*)d_in[15];
  float* out = (float*)d_out;
  float* ws  = (float*)d_ws;

  hipLaunchKernelGGL(k_pre, dim3(9), dim3(64), 0, stream,
                     h_t, W_f1, b_f1, W_g1, b_g1, W_mu, b_mu, W_sig, b_sig, out, ws);
  hipLaunchKernelGGL(k_sde, dim3(BN / 64), dim3(64), 0, stream,
                     ip, W_f1, W_f2, b_f2, W_f3, b_f3, W_g1, W_g2, b_g2, out, ws);
}